// Round 19
// baseline (140.488 us; speedup 1.0000x reference)
//
#include <hip/hip_runtime.h>
#include <hip/hip_bf16.h>
#include <cstdint>

#define DEV __device__ __forceinline__

constexpr int B = 64, T = 1024, N = 512, D = 64, K = 80;

typedef __attribute__((ext_vector_type(8))) short bf16x8;
typedef __attribute__((ext_vector_type(4))) float f32x4;

DEV float fast_tanh(float x) {
    x = fminf(fmaxf(x, -15.f), 15.f);
    float e = __expf(2.f * x);
    return 1.f - 2.f * __builtin_amdgcn_rcpf(e + 1.f);
}

DEV unsigned short f2bf(float f) {
    unsigned int u = __float_as_uint(f);
    unsigned int r = (u + 0x7fffu + ((u >> 16) & 1u)) >> 16;
    return (unsigned short)r;
}
DEV float bf2f(unsigned short s) {
    return __uint_as_float(((unsigned int)s) << 16);
}

DEV unsigned short cvt_bf16(float v) {
    __hip_bfloat16 h = __float2bfloat16(v);
    return *reinterpret_cast<unsigned short*>(&h);
}

// Async global->LDS DMA, 16B/lane: LDS dst = wave-uniform base + lane*16;
// global src = per-lane address.
DEV void gload16(const unsigned short* src, unsigned short* dst) {
    __builtin_amdgcn_global_load_lds(
        (const __attribute__((address_space(1))) void*)src,
        (__attribute__((address_space(3))) void*)dst,
        16, 0, 0);
}

// Fragment-native tiled layout: off(row,col) = ((row/16)*(S/8)+col/8)*128
//                                             + (row%16)*8 + (col%8)
DEV size_t tix(size_t row, int col, int S8) {
    return (((row >> 4) * S8 + (size_t)(col >> 3)) << 7) + ((row & 15) << 3) + (col & 7);
}

#define MFMA(a, b, c) __builtin_amdgcn_mfma_f32_16x16x32_bf16((a), (b), (c), 0, 0, 0)

// ===========================================================================
// Prelude bodies (one merged dispatch)
// ===========================================================================

// M[b,t,:] = review[b,t,:] @ Wl. v19: 4x4 register blocking. Thread (ty,tx)
// owns rows ty*4..+3 x cols tx*4..+3: per d-step, 1 float4 W read + 4 scalar
// Rs reads feed 16 FMAs -> 320 LDS insts/thread (was ~1088, LDS-issue bound).
// Rs padded to [65] (kills the 4-way same-bank conflict of column reads).
DEV void matWl_body(int bid, char* lds, const float* __restrict__ review,
                    const float* __restrict__ Wl,
                    unsigned short* __restrict__ Mhi, unsigned short* __restrict__ Mlo) {
    float (*Wls)[64] = reinterpret_cast<float(*)[64]>(lds);          // 16,384 B
    float (*Rs)[65]  = reinterpret_cast<float(*)[65]>(lds + 16384);  // 16,640 B
    int tid = threadIdx.x;
    size_t base = (size_t)bid * 4096;
#pragma unroll
    for (int i = 0; i < 16; i++) {
        int e = tid + i * 256;
        Wls[e >> 6][e & 63] = Wl[e];
        Rs[e >> 6][e & 63] = review[base + e];
    }
    __syncthreads();
    int tx = tid & 15, ty = tid >> 4;   // cols tx*4..+3, rows ty*4..+3
    float acc[4][4];
#pragma unroll
    for (int r = 0; r < 4; r++)
#pragma unroll
        for (int c = 0; c < 4; c++) acc[r][c] = 0.f;
    for (int d = 0; d < 64; d++) {
        float4 w = *reinterpret_cast<const float4*>(&Wls[d][tx * 4]);
        float r0 = Rs[ty * 4 + 0][d];
        float r1 = Rs[ty * 4 + 1][d];
        float r2 = Rs[ty * 4 + 2][d];
        float r3 = Rs[ty * 4 + 3][d];
        acc[0][0] += r0 * w.x; acc[0][1] += r0 * w.y; acc[0][2] += r0 * w.z; acc[0][3] += r0 * w.w;
        acc[1][0] += r1 * w.x; acc[1][1] += r1 * w.y; acc[1][2] += r1 * w.z; acc[1][3] += r1 * w.w;
        acc[2][0] += r2 * w.x; acc[2][1] += r2 * w.y; acc[2][2] += r2 * w.z; acc[2][3] += r2 * w.w;
        acc[3][0] += r3 * w.x; acc[3][1] += r3 * w.y; acc[3][2] += r3 * w.z; acc[3][3] += r3 * w.w;
    }
    // tix keeps 4 consecutive cols (within an 8-col group) contiguous: the
    // 4 cols tx*4..+3 share col>>3, so hi/lo writes are ushort4 stores.
#pragma unroll
    for (int r = 0; r < 4; r++) {
        size_t row = (size_t)bid * 64 + ty * 4 + r;
        size_t o = tix(row, tx * 4, 8);
        ushort4 h, lo;
        h.x = f2bf(acc[r][0]); lo.x = f2bf(acc[r][0] - bf2f(h.x));
        h.y = f2bf(acc[r][1]); lo.y = f2bf(acc[r][1] - bf2f(h.y));
        h.z = f2bf(acc[r][2]); lo.z = f2bf(acc[r][2] - bf2f(h.z));
        h.w = f2bf(acc[r][3]); lo.w = f2bf(acc[r][3] - bf2f(h.w));
        *reinterpret_cast<ushort4*>(Mhi + o) = h;
        *reinterpret_cast<ushort4*>(Mlo + o) = lo;
    }
}

DEV void split_body(int bid, const float* __restrict__ X,
                    unsigned short* __restrict__ Xhi, unsigned short* __restrict__ Xlo) {
    int i = bid * 256 + threadIdx.x;
    float4 v = *reinterpret_cast<const float4*>(X + (size_t)i * 4);
    ushort4 h, lo;
    h.x = f2bf(v.x); lo.x = f2bf(v.x - bf2f(h.x));
    h.y = f2bf(v.y); lo.y = f2bf(v.y - bf2f(h.y));
    h.z = f2bf(v.z); lo.z = f2bf(v.z - bf2f(h.z));
    h.w = f2bf(v.w); lo.w = f2bf(v.w - bf2f(h.w));
    size_t o = tix((size_t)(i >> 4), (i & 15) * 4, 8);
    *reinterpret_cast<ushort4*>(Xhi + o) = h;
    *reinterpret_cast<ushort4*>(Xlo + o) = lo;
}

DEV void proj_body(int sx, int b, char* lds, const float* __restrict__ W,
                   const float* __restrict__ X,
                   unsigned short* __restrict__ Phi, unsigned short* __restrict__ Plo, int S) {
    float (*Ws)[64] = reinterpret_cast<float(*)[64]>(lds);
    float (*Xs)[65] = reinterpret_cast<float(*)[65]>(lds + 20480);
    int tid = threadIdx.x, tx = tid & 63, ty = tid >> 6;
    int s0 = sx * 64;
#pragma unroll
    for (int i = 0; i < 20; i++) { int e = tid + i * 256; Ws[e >> 6][e & 63] = W[e]; }
    const float* Xp = X + ((size_t)b * S + s0) * 64;
#pragma unroll
    for (int i = 0; i < 16; i++) { int e = tid + i * 256; Xs[e >> 6][e & 63] = Xp[e]; }
    __syncthreads();
    float acc[20];
#pragma unroll
    for (int kk = 0; kk < 20; kk++) acc[kk] = 0.f;
    for (int d = 0; d < 64; d += 4) {
        float x0 = Xs[tx][d], x1 = Xs[tx][d + 1], x2 = Xs[tx][d + 2], x3 = Xs[tx][d + 3];
#pragma unroll
        for (int kk = 0; kk < 20; kk++) {
            const float4 w = *reinterpret_cast<const float4*>(&Ws[ty * 20 + kk][d]);
            acc[kk] += w.x * x0 + w.y * x1 + w.z * x2 + w.w * x3;
        }
    }
    int S8 = S >> 3;
#pragma unroll
    for (int kk = 0; kk < 20; kk++) {
        size_t idx = tix((size_t)b * K + ty * 20 + kk, s0 + tx, S8);
        float v = acc[kk];
        unsigned short h = f2bf(v);
        Phi[idx] = h;
        Plo[idx] = f2bf(v - bf2f(h));
    }
}

__global__ __launch_bounds__(256) void k_prelude(
    const float* __restrict__ review, const float* __restrict__ post,
    const float* __restrict__ Wl, const float* __restrict__ Wr,
    const float* __restrict__ Wp,
    unsigned short* __restrict__ Mhi, unsigned short* __restrict__ Mlo,
    unsigned short* __restrict__ PsH, unsigned short* __restrict__ PsL,
    unsigned short* __restrict__ Rhi, unsigned short* __restrict__ Rlo,
    unsigned short* __restrict__ Phi, unsigned short* __restrict__ Plo,
    float* __restrict__ out) {
    __shared__ __align__(16) char lds[37120];
    int bid = blockIdx.x;
    if (bid < 1024) {
        matWl_body(bid, lds, review, Wl, Mhi, Mlo);
    } else if (bid < 3072) {
        split_body(bid - 1024, post, PsH, PsL);
    } else if (bid < 4096) {
        int i = bid - 3072;
        proj_body(i & 15, i >> 4, lds, Wr, review, Rhi, Rlo, T);
    } else if (bid < 4608) {
        int i = bid - 4096;
        proj_body(i & 7, i >> 3, lds, Wp, post, Phi, Plo, N);
    } else {
        int i = bid - 4608;
        out[(size_t)i * 256 + threadIdx.x] = 0.f;
    }
}

// ===========================================================================
// Fused hp/hr bodies (v18: phase-split async staging + setprio) — UNCHANGED.
// ===========================================================================

DEV void hp_body(int b, int nc0, unsigned short* smem,
                 const unsigned short* __restrict__ Mhi, const unsigned short* __restrict__ Mlo,
                 const unsigned short* __restrict__ PsH, const unsigned short* __restrict__ PsL,
                 const unsigned short* __restrict__ Rhi, const unsigned short* __restrict__ Rlo,
                 const unsigned short* __restrict__ Phi, const unsigned short* __restrict__ Plo,
                 const float* __restrict__ whp, float* __restrict__ logits_p) {
    unsigned short* MH_l = smem;
    unsigned short* ML_l = smem + 4096;
    unsigned short* RH_l = smem + 8192;
    unsigned short* RL_l = smem + 13312;
    typedef unsigned short LtRow[72];
    LtRow* Lt = reinterpret_cast<LtRow*>(smem + 18432);
    int tid = threadIdx.x, l = tid & 63, wv = tid >> 6;
    int lr = l & 15, lg = l >> 4;

    size_t prow = (size_t)b * N + nc0 + wv * 16 + lr;
    size_t p0 = tix(prow, lg * 8, 8), p1 = tix(prow, 32 + lg * 8, 8);
    bf16x8 pah0 = *reinterpret_cast<const bf16x8*>(PsH + p0);
    bf16x8 pah1 = *reinterpret_cast<const bf16x8*>(PsH + p1);
    bf16x8 pal0 = *reinterpret_cast<const bf16x8*>(PsL + p0);
    bf16x8 pal1 = *reinterpret_cast<const bf16x8*>(PsL + p1);

    const unsigned short* srcp[9];
    unsigned short* dstp[9];
    int strd[9];
#pragma unroll
    for (int i = 0; i < 9; i++) {
        int c = wv + i * 4;
        if (c < 8) {
            srcp[i] = Mhi + (size_t)b * T * 64 + c * 512;
            dstp[i] = MH_l + c * 512;
            strd[i] = 4096;
        } else if (c < 16) {
            srcp[i] = Mlo + (size_t)b * T * 64 + (c - 8) * 512;
            dstp[i] = ML_l + (c - 8) * 512;
            strd[i] = 4096;
        } else {
            int j = c - 16, jj = (j < 10) ? j : j - 10;
            int rg = jj >> 1, half = jj & 1;
            srcp[i] = ((j < 10) ? Rhi : Rlo) + (size_t)(b * 5 + rg) * 16384 + half * 512;
            dstp[i] = ((j < 10) ? RH_l : RL_l) + rg * 1024 + half * 512;
            strd[i] = 1024;
        }
        srcp[i] += l * 8;
    }

    f32x4 hp[5];
#pragma unroll
    for (int f = 0; f < 5; f++) hp[f] = (f32x4){0.f, 0.f, 0.f, 0.f};

#pragma unroll
    for (int i = 0; i < 4; i++) { gload16(srcp[i], dstp[i]); srcp[i] += strd[i]; }
    __syncthreads();
#pragma unroll
    for (int i = 4; i < 9; i++) { gload16(srcp[i], dstp[i]); srcp[i] += strd[i]; }

    for (int tt = 0; tt < 16; tt++) {
        __builtin_amdgcn_s_setprio(1);
#pragma unroll
        for (int tf = 0; tf < 4; tf++) {
            int o0 = tf * 1024 + lg * 128 + lr * 8;
            int o1 = tf * 1024 + (4 + lg) * 128 + lr * 8;
            bf16x8 mh0 = *reinterpret_cast<const bf16x8*>(MH_l + o0);
            bf16x8 mh1 = *reinterpret_cast<const bf16x8*>(MH_l + o1);
            bf16x8 ml0 = *reinterpret_cast<const bf16x8*>(ML_l + o0);
            bf16x8 ml1 = *reinterpret_cast<const bf16x8*>(ML_l + o1);
            f32x4 a = (f32x4){0.f, 0.f, 0.f, 0.f};
            a = MFMA(pah0, mh0, a);
            a = MFMA(pah0, ml0, a);
            a = MFMA(pal0, mh0, a);
            a = MFMA(pah1, mh1, a);
            a = MFMA(pah1, ml1, a);
            a = MFMA(pal1, mh1, a);
#pragma unroll
            for (int r = 0; r < 4; r++)
                Lt[wv * 16 + lg * 4 + r][tf * 16 + lr] = cvt_bf16(fast_tanh(a[r]));
        }
        __builtin_amdgcn_s_setprio(0);
        __syncthreads();                    // drains R(tt); M free
        if (tt < 15) {
#pragma unroll
            for (int i = 0; i < 4; i++) { gload16(srcp[i], dstp[i]); srcp[i] += strd[i]; }
        }
        bf16x8 bt0 = *reinterpret_cast<const bf16x8*>(&Lt[wv * 16 + lr][lg * 8]);
        bf16x8 bt1 = *reinterpret_cast<const bf16x8*>(&Lt[wv * 16 + lr][32 + lg * 8]);
        __builtin_amdgcn_s_setprio(1);
#pragma unroll
        for (int kf = 0; kf < 5; kf++) {
            int o0 = kf * 1024 + lg * 128 + lr * 8;
            int o1 = kf * 1024 + (4 + lg) * 128 + lr * 8;
            bf16x8 rh0 = *reinterpret_cast<const bf16x8*>(RH_l + o0);
            bf16x8 rh1 = *reinterpret_cast<const bf16x8*>(RH_l + o1);
            bf16x8 rl0 = *reinterpret_cast<const bf16x8*>(RL_l + o0);
            bf16x8 rl1 = *reinterpret_cast<const bf16x8*>(RL_l + o1);
            hp[kf] = MFMA(rh0, bt0, hp[kf]);
            hp[kf] = MFMA(rl0, bt0, hp[kf]);
            hp[kf] = MFMA(rh1, bt1, hp[kf]);
            hp[kf] = MFMA(rl1, bt1, hp[kf]);
        }
        __builtin_amdgcn_s_setprio(0);
        __syncthreads();                    // drains M(tt+1); R free
        if (tt < 15) {
#pragma unroll
            for (int i = 4; i < 9; i++) { gload16(srcp[i], dstp[i]); srcp[i] += strd[i]; }
        }
    }

    int n = nc0 + wv * 16 + lr;
    float partial = 0.f;
#pragma unroll
    for (int kf = 0; kf < 5; kf++)
#pragma unroll
        for (int r = 0; r < 4; r++) {
            int k = kf * 16 + lg * 4 + r;
            size_t idx = tix((size_t)b * K + k, n, 64);
            float pp = bf2f(Phi[idx]) + bf2f(Plo[idx]);
            partial += whp[k] * fast_tanh(pp + hp[kf][r]);
        }
    partial += __shfl_xor(partial, 16);
    partial += __shfl_xor(partial, 32);
    if (lg == 0) logits_p[(size_t)b * N + n] = partial;
}

DEV void hr_body(int b, int tc0, unsigned short* smem,
                 const unsigned short* __restrict__ Mhi, const unsigned short* __restrict__ Mlo,
                 const unsigned short* __restrict__ PsH, const unsigned short* __restrict__ PsL,
                 const unsigned short* __restrict__ Phi, const unsigned short* __restrict__ Plo,
                 const unsigned short* __restrict__ Rhi, const unsigned short* __restrict__ Rlo,
                 const float* __restrict__ whr, float* __restrict__ logits_r) {
    unsigned short* PsH_l = smem;
    unsigned short* PsL_l = smem + 4096;
    unsigned short* PpH_l = smem + 8192;
    unsigned short* PpL_l = smem + 13312;
    typedef unsigned short LtRow[72];
    LtRow* Lt = reinterpret_cast<LtRow*>(smem + 18432);
    int tid = threadIdx.x, l = tid & 63, wv = tid >> 6;
    int lr = l & 15, lg = l >> 4;

    size_t mrow = (size_t)b * T + tc0 + wv * 16 + lr;
    size_t m0 = tix(mrow, lg * 8, 8), m1 = tix(mrow, 32 + lg * 8, 8);
    bf16x8 mh0 = *reinterpret_cast<const bf16x8*>(Mhi + m0);
    bf16x8 mh1 = *reinterpret_cast<const bf16x8*>(Mhi + m1);
    bf16x8 ml0 = *reinterpret_cast<const bf16x8*>(Mlo + m0);
    bf16x8 ml1 = *reinterpret_cast<const bf16x8*>(Mlo + m1);

    const unsigned short* srcp[9];
    unsigned short* dstp[9];
    int strd[9];
#pragma unroll
    for (int i = 0; i < 9; i++) {
        int c = wv + i * 4;
        if (c < 8) {
            srcp[i] = PsH + (size_t)b * N * 64 + c * 512;
            dstp[i] = PsH_l + c * 512;
            strd[i] = 4096;
        } else if (c < 16) {
            srcp[i] = PsL + (size_t)b * N * 64 + (c - 8) * 512;
            dstp[i] = PsL_l + (c - 8) * 512;
            strd[i] = 4096;
        } else {
            int j = c - 16, jj = (j < 10) ? j : j - 10;
            int rg = jj >> 1, half = jj & 1;
            srcp[i] = ((j < 10) ? Phi : Plo) + (size_t)(b * 5 + rg) * 8192 + half * 512;
            dstp[i] = ((j < 10) ? PpH_l : PpL_l) + rg * 1024 + half * 512;
            strd[i] = 1024;
        }
        srcp[i] += l * 8;
    }

    f32x4 hr[5];
#pragma unroll
    for (int f = 0; f < 5; f++) hr[f] = (f32x4){0.f, 0.f, 0.f, 0.f};

#pragma unroll
    for (int i = 0; i < 4; i++) { gload16(srcp[i], dstp[i]); srcp[i] += strd[i]; }
    __syncthreads();
#pragma unroll
    for (int i = 4; i < 9; i++) { gload16(srcp[i], dstp[i]); srcp[i] += strd[i]; }

    for (int nt = 0; nt < 8; nt++) {
        __builtin_amdgcn_s_setprio(1);
#pragma unroll
        for (int nf = 0; nf < 4; nf++) {
            int o0 = nf * 1024 + lg * 128 + lr * 8;
            int o1 = nf * 1024 + (4 + lg) * 128 + lr * 8;
            bf16x8 ph0 = *reinterpret_cast<const bf16x8*>(PsH_l + o0);
            bf16x8 ph1 = *reinterpret_cast<const bf16x8*>(PsH_l + o1);
            bf16x8 pl0 = *reinterpret_cast<const bf16x8*>(PsL_l + o0);
            bf16x8 pl1 = *reinterpret_cast<const bf16x8*>(PsL_l + o1);
            f32x4 a = (f32x4){0.f, 0.f, 0.f, 0.f};
            a = MFMA(mh0, ph0, a);
            a = MFMA(mh0, pl0, a);
            a = MFMA(ml0, ph0, a);
            a = MFMA(mh1, ph1, a);
            a = MFMA(mh1, pl1, a);
            a = MFMA(ml1, ph1, a);
#pragma unroll
            for (int r = 0; r < 4; r++)
                Lt[wv * 16 + lg * 4 + r][nf * 16 + lr] = cvt_bf16(fast_tanh(a[r]));
        }
        __builtin_amdgcn_s_setprio(0);
        __syncthreads();
        if (nt < 7) {
#pragma unroll
            for (int i = 0; i < 4; i++) { gload16(srcp[i], dstp[i]); srcp[i] += strd[i]; }
        }
        bf16x8 bt0 = *reinterpret_cast<const bf16x8*>(&Lt[wv * 16 + lr][lg * 8]);
        bf16x8 bt1 = *reinterpret_cast<const bf16x8*>(&Lt[wv * 16 + lr][32 + lg * 8]);
        __builtin_amdgcn_s_setprio(1);
#pragma unroll
        for (int kf = 0; kf < 5; kf++) {
            int o0 = kf * 1024 + lg * 128 + lr * 8;
            int o1 = kf * 1024 + (4 + lg) * 128 + lr * 8;
            bf16x8 qh0 = *reinterpret_cast<const bf16x8*>(PpH_l + o0);
            bf16x8 qh1 = *reinterpret_cast<const bf16x8*>(PpH_l + o1);
            bf16x8 ql0 = *reinterpret_cast<const bf16x8*>(PpL_l + o0);
            bf16x8 ql1 = *reinterpret_cast<const bf16x8*>(PpL_l + o1);
            hr[kf] = MFMA(qh0, bt0, hr[kf]);
            hr[kf] = MFMA(ql0, bt0, hr[kf]);
            hr[kf] = MFMA(qh1, bt1, hr[kf]);
            hr[kf] = MFMA(ql1, bt1, hr[kf]);
        }
        __builtin_amdgcn_s_setprio(0);
        __syncthreads();
        if (nt < 7) {
#pragma unroll
            for (int i = 4; i < 9; i++) { gload16(srcp[i], dstp[i]); srcp[i] += strd[i]; }
        }
    }

    int t = tc0 + wv * 16 + lr;
    float partial = 0.f;
#pragma unroll
    for (int kf = 0; kf < 5; kf++)
#pragma unroll
        for (int r = 0; r < 4; r++) {
            int k = kf * 16 + lg * 4 + r;
            size_t idx = tix((size_t)b * K + k, t, 128);
            float rr = bf2f(Rhi[idx]) + bf2f(Rlo[idx]);
            partial += whr[k] * fast_tanh(rr + hr[kf][r]);
        }
    partial += __shfl_xor(partial, 16);
    partial += __shfl_xor(partial, 32);
    if (lg == 0) logits_r[(size_t)b * T + t] = partial;
}

// ---------------------------------------------------------------------------
// Merged fused kernel (v13 grid): per b, 24 roles (8 hp + 16 hr).
// lin = (b%8) + 8*((b/8)*24 + role): all of a b's blocks on one XCD.
__global__ __launch_bounds__(256) void k_fused(
    const unsigned short* __restrict__ Mhi, const unsigned short* __restrict__ Mlo,
    const unsigned short* __restrict__ PsH, const unsigned short* __restrict__ PsL,
    const unsigned short* __restrict__ Rhi, const unsigned short* __restrict__ Rlo,
    const unsigned short* __restrict__ Phi, const unsigned short* __restrict__ Plo,
    const float* __restrict__ whp, const float* __restrict__ whr,
    float* __restrict__ logits_p, float* __restrict__ logits_r) {
    __shared__ __align__(16) unsigned short smem[23040];   // 46,080 B
    int lin = blockIdx.x;
    int x = lin & 7, j = lin >> 3;
    int bg = j / 24, role = j - bg * 24;
    int b = bg * 8 + x;
    if (role < 8) {
        hp_body(b, role * 64, smem, Mhi, Mlo, PsH, PsL, Rhi, Rlo, Phi, Plo, whp, logits_p);
    } else {
        hr_body(b, (role - 8) * 64, smem, Mhi, Mlo, PsH, PsL, Phi, Plo, Rhi, Rlo, whr, logits_r);
    }
}

// ===========================================================================
// Merged softpool
// ===========================================================================
DEV void softpool_body(const float* __restrict__ logits, const float* __restrict__ X,
                       float* __restrict__ out, int S, int off, int cy,
                       float* sm, float* red) {
    int b = blockIdx.x, tid = threadIdx.x;
    int c0 = cy * 128;
    for (int i = tid; i < S; i += 256) sm[i] = logits[(size_t)b * S + i];
    __syncthreads();
    float m = -1e30f;
    for (int i = tid; i < S; i += 256) m = fmaxf(m, sm[i]);
    red[tid] = m;
    __syncthreads();
    for (int s = 128; s > 0; s >>= 1) {
        if (tid < s) red[tid] = fmaxf(red[tid], red[tid + s]);
        __syncthreads();
    }
    float mx = red[0];
    __syncthreads();
    float psum = 0.f;
    for (int i = tid; i < S; i += 256) {
        float e = __expf(sm[i] - mx);
        sm[i] = e;
        psum += e;
    }
    red[tid] = psum;
    __syncthreads();
    for (int s = 128; s > 0; s >>= 1) {
        if (tid < s) red[tid] += red[tid + s];
        __syncthreads();
    }
    float inv = 1.f / red[0];
    __syncthreads();
    int d = tid & 63, g = tid >> 6;
    float acc = 0.f;
    for (int n = c0 + g; n < c0 + 128; n += 4) acc += sm[n] * X[((size_t)b * S + n) * 64 + d];
    red[tid] = acc * inv;
    __syncthreads();
    if (g == 0)
        atomicAdd(&out[(size_t)b * 128 + off + d],
                  red[d] + red[64 + d] + red[128 + d] + red[192 + d]);
}

__global__ __launch_bounds__(256) void k_softpool2(
    const float* __restrict__ logits_p, const float* __restrict__ logits_r,
    const float* __restrict__ post, const float* __restrict__ review,
    float* __restrict__ out) {
    __shared__ float sm[1024];
    __shared__ float red[256];
    int y = blockIdx.y;
    if (y < N / 128) softpool_body(logits_p, post, out, N, 0, y, sm, red);
    else             softpool_body(logits_r, review, out, T, 64, y - N / 128, sm, red);
}

// ---------------------------------------------------------------------------
extern "C" void kernel_launch(void* const* d_in, const int* in_sizes, int n_in,
                              void* d_out, int out_size, void* d_ws, size_t ws_size,
                              hipStream_t stream) {
    const float* review = (const float*)d_in[0];
    const float* post   = (const float*)d_in[1];
    const float* Wl     = (const float*)d_in[2];
    const float* Wr     = (const float*)d_in[3];
    const float* Wp     = (const float*)d_in[4];
    const float* whr    = (const float*)d_in[5];
    const float* whp    = (const float*)d_in[6];
    float* out = (float*)d_out;

    char* p = (char*)d_ws;
    unsigned short* Mhi = (unsigned short*)p;  p += (size_t)B * T * D * 2;
    unsigned short* Mlo = (unsigned short*)p;  p += (size_t)B * T * D * 2;
    unsigned short* PsH = (unsigned short*)p;  p += (size_t)B * N * D * 2;
    unsigned short* PsL = (unsigned short*)p;  p += (size_t)B * N * D * 2;
    unsigned short* Rhi = (unsigned short*)p;  p += (size_t)B * K * T * 2;
    unsigned short* Rlo = (unsigned short*)p;  p += (size_t)B * K * T * 2;
    unsigned short* Phi = (unsigned short*)p;  p += (size_t)B * K * N * 2;
    unsigned short* Plo = (unsigned short*)p;  p += (size_t)B * K * N * 2;
    float* logits_p = (float*)p;        p += (size_t)B * N * 4;
    float* logits_r = (float*)p;        p += (size_t)B * T * 4;

    k_prelude<<<dim3(4640), dim3(256), 0, stream>>>(review, post, Wl, Wr, Wp,
                                                    Mhi, Mlo, PsH, PsL, Rhi, Rlo,
                                                    Phi, Plo, out);
    k_fused<<<dim3(1536), dim3(256), 0, stream>>>(Mhi, Mlo, PsH, PsL, Rhi, Rlo,
                                                  Phi, Plo, whp, whr, logits_p, logits_r);
    k_softpool2<<<dim3(B, 12), dim3(256), 0, stream>>>(logits_p, logits_r, post, review, out);
}

// Round 20
// 136.146 us; speedup vs baseline: 1.0319x; 1.0319x over previous
//
#include <hip/hip_runtime.h>
#include <hip/hip_bf16.h>
#include <cstdint>

#define DEV __device__ __forceinline__

constexpr int B = 64, T = 1024, N = 512, D = 64, K = 80;

typedef __attribute__((ext_vector_type(8))) short bf16x8;
typedef __attribute__((ext_vector_type(4))) float f32x4;

// tanh = 1 - 2/(e^{2x}+1). No clamp needed: x=+inf -> e=inf -> rcp=0 -> 1;
// x=-inf -> e=0 -> 1-2 = -1. Finite for all finite x (e+1 >= 1).
DEV float fast_tanh(float x) {
    float e = __expf(2.f * x);
    return 1.f - 2.f * __builtin_amdgcn_rcpf(e + 1.f);
}

DEV unsigned short f2bf(float f) {
    unsigned int u = __float_as_uint(f);
    unsigned int r = (u + 0x7fffu + ((u >> 16) & 1u)) >> 16;
    return (unsigned short)r;
}
DEV float bf2f(unsigned short s) {
    return __uint_as_float(((unsigned int)s) << 16);
}

DEV unsigned short cvt_bf16(float v) {
    __hip_bfloat16 h = __float2bfloat16(v);
    return *reinterpret_cast<unsigned short*>(&h);
}

// Async global->LDS DMA, 16B/lane: LDS dst = wave-uniform base + lane*16;
// global src = per-lane address.
DEV void gload16(const unsigned short* src, unsigned short* dst) {
    __builtin_amdgcn_global_load_lds(
        (const __attribute__((address_space(1))) void*)src,
        (__attribute__((address_space(3))) void*)dst,
        16, 0, 0);
}

// Fragment-native tiled layout: off(row,col) = ((row/16)*(S/8)+col/8)*128
//                                             + (row%16)*8 + (col%8)
DEV size_t tix(size_t row, int col, int S8) {
    return (((row >> 4) * S8 + (size_t)(col >> 3)) << 7) + ((row & 15) << 3) + (col & 7);
}

#define MFMA(a, b, c) __builtin_amdgcn_mfma_f32_16x16x32_bf16((a), (b), (c), 0, 0, 0)

// ===========================================================================
// Prelude bodies (one merged dispatch) — v18 versions.
// ===========================================================================

DEV void matWl_body(int bid, char* lds, const float* __restrict__ review,
                    const float* __restrict__ Wl,
                    unsigned short* __restrict__ Mhi, unsigned short* __restrict__ Mlo) {
    float (*Wls)[64] = reinterpret_cast<float(*)[64]>(lds);
    float (*Rs)[64]  = reinterpret_cast<float(*)[64]>(lds + 16384);
    int tid = threadIdx.x;
    size_t base = (size_t)bid * 4096;
#pragma unroll
    for (int i = 0; i < 16; i++) {
        int e = tid + i * 256;
        Wls[e >> 6][e & 63] = Wl[e];
        Rs[e >> 6][e & 63] = review[base + e];
    }
    __syncthreads();
    int c = tid & 63, r0 = tid >> 6;
    float acc[16];
#pragma unroll
    for (int i = 0; i < 16; i++) acc[i] = 0.f;
    for (int d = 0; d < 64; d += 2) {
        float w0 = Wls[d][c], w1 = Wls[d + 1][c];
#pragma unroll
        for (int i = 0; i < 16; i++)
            acc[i] += Rs[r0 * 16 + i][d] * w0 + Rs[r0 * 16 + i][d + 1] * w1;
    }
#pragma unroll
    for (int i = 0; i < 16; i++) {
        size_t row = (size_t)bid * 64 + r0 * 16 + i;
        size_t o = tix(row, c, 8);
        unsigned short h = f2bf(acc[i]);
        Mhi[o] = h;
        Mlo[o] = f2bf(acc[i] - bf2f(h));
    }
}

DEV void split_body(int bid, const float* __restrict__ X,
                    unsigned short* __restrict__ Xhi, unsigned short* __restrict__ Xlo) {
    int i = bid * 256 + threadIdx.x;
    float4 v = *reinterpret_cast<const float4*>(X + (size_t)i * 4);
    ushort4 h, lo;
    h.x = f2bf(v.x); lo.x = f2bf(v.x - bf2f(h.x));
    h.y = f2bf(v.y); lo.y = f2bf(v.y - bf2f(h.y));
    h.z = f2bf(v.z); lo.z = f2bf(v.z - bf2f(h.z));
    h.w = f2bf(v.w); lo.w = f2bf(v.w - bf2f(h.w));
    size_t o = tix((size_t)(i >> 4), (i & 15) * 4, 8);
    *reinterpret_cast<ushort4*>(Xhi + o) = h;
    *reinterpret_cast<ushort4*>(Xlo + o) = lo;
}

DEV void proj_body(int sx, int b, char* lds, const float* __restrict__ W,
                   const float* __restrict__ X,
                   unsigned short* __restrict__ Phi, unsigned short* __restrict__ Plo, int S) {
    float (*Ws)[64] = reinterpret_cast<float(*)[64]>(lds);
    float (*Xs)[65] = reinterpret_cast<float(*)[65]>(lds + 20480);
    int tid = threadIdx.x, tx = tid & 63, ty = tid >> 6;
    int s0 = sx * 64;
#pragma unroll
    for (int i = 0; i < 20; i++) { int e = tid + i * 256; Ws[e >> 6][e & 63] = W[e]; }
    const float* Xp = X + ((size_t)b * S + s0) * 64;
#pragma unroll
    for (int i = 0; i < 16; i++) { int e = tid + i * 256; Xs[e >> 6][e & 63] = Xp[e]; }
    __syncthreads();
    float acc[20];
#pragma unroll
    for (int kk = 0; kk < 20; kk++) acc[kk] = 0.f;
    for (int d = 0; d < 64; d += 4) {
        float x0 = Xs[tx][d], x1 = Xs[tx][d + 1], x2 = Xs[tx][d + 2], x3 = Xs[tx][d + 3];
#pragma unroll
        for (int kk = 0; kk < 20; kk++) {
            const float4 w = *reinterpret_cast<const float4*>(&Ws[ty * 20 + kk][d]);
            acc[kk] += w.x * x0 + w.y * x1 + w.z * x2 + w.w * x3;
        }
    }
    int S8 = S >> 3;
#pragma unroll
    for (int kk = 0; kk < 20; kk++) {
        size_t idx = tix((size_t)b * K + ty * 20 + kk, s0 + tx, S8);
        float v = acc[kk];
        unsigned short h = f2bf(v);
        Phi[idx] = h;
        Plo[idx] = f2bf(v - bf2f(h));
    }
}

__global__ __launch_bounds__(256) void k_prelude(
    const float* __restrict__ review, const float* __restrict__ post,
    const float* __restrict__ Wl, const float* __restrict__ Wr,
    const float* __restrict__ Wp,
    unsigned short* __restrict__ Mhi, unsigned short* __restrict__ Mlo,
    unsigned short* __restrict__ PsH, unsigned short* __restrict__ PsL,
    unsigned short* __restrict__ Rhi, unsigned short* __restrict__ Rlo,
    unsigned short* __restrict__ Phi, unsigned short* __restrict__ Plo,
    float* __restrict__ out) {
    __shared__ __align__(16) char lds[37120];
    int bid = blockIdx.x;
    if (bid < 1024) {
        matWl_body(bid, lds, review, Wl, Mhi, Mlo);
    } else if (bid < 3072) {
        split_body(bid - 1024, post, PsH, PsL);
    } else if (bid < 4096) {
        int i = bid - 3072;
        proj_body(i & 15, i >> 4, lds, Wr, review, Rhi, Rlo, T);
    } else if (bid < 4608) {
        int i = bid - 4096;
        proj_body(i & 7, i >> 3, lds, Wp, post, Phi, Plo, N);
    } else {
        int i = bid - 4608;
        out[(size_t)i * 256 + threadIdx.x] = 0.f;
    }
}

// ===========================================================================
// Fused hp/hr bodies (v18: phase-split async staging + setprio) — unchanged
// except the cheaper unclamped tanh.
// ===========================================================================

DEV void hp_body(int b, int nc0, unsigned short* smem,
                 const unsigned short* __restrict__ Mhi, const unsigned short* __restrict__ Mlo,
                 const unsigned short* __restrict__ PsH, const unsigned short* __restrict__ PsL,
                 const unsigned short* __restrict__ Rhi, const unsigned short* __restrict__ Rlo,
                 const unsigned short* __restrict__ Phi, const unsigned short* __restrict__ Plo,
                 const float* __restrict__ whp, float* __restrict__ logits_p) {
    unsigned short* MH_l = smem;
    unsigned short* ML_l = smem + 4096;
    unsigned short* RH_l = smem + 8192;
    unsigned short* RL_l = smem + 13312;
    typedef unsigned short LtRow[72];
    LtRow* Lt = reinterpret_cast<LtRow*>(smem + 18432);
    int tid = threadIdx.x, l = tid & 63, wv = tid >> 6;
    int lr = l & 15, lg = l >> 4;

    size_t prow = (size_t)b * N + nc0 + wv * 16 + lr;
    size_t p0 = tix(prow, lg * 8, 8), p1 = tix(prow, 32 + lg * 8, 8);
    bf16x8 pah0 = *reinterpret_cast<const bf16x8*>(PsH + p0);
    bf16x8 pah1 = *reinterpret_cast<const bf16x8*>(PsH + p1);
    bf16x8 pal0 = *reinterpret_cast<const bf16x8*>(PsL + p0);
    bf16x8 pal1 = *reinterpret_cast<const bf16x8*>(PsL + p1);

    const unsigned short* srcp[9];
    unsigned short* dstp[9];
    int strd[9];
#pragma unroll
    for (int i = 0; i < 9; i++) {
        int c = wv + i * 4;
        if (c < 8) {
            srcp[i] = Mhi + (size_t)b * T * 64 + c * 512;
            dstp[i] = MH_l + c * 512;
            strd[i] = 4096;
        } else if (c < 16) {
            srcp[i] = Mlo + (size_t)b * T * 64 + (c - 8) * 512;
            dstp[i] = ML_l + (c - 8) * 512;
            strd[i] = 4096;
        } else {
            int j = c - 16, jj = (j < 10) ? j : j - 10;
            int rg = jj >> 1, half = jj & 1;
            srcp[i] = ((j < 10) ? Rhi : Rlo) + (size_t)(b * 5 + rg) * 16384 + half * 512;
            dstp[i] = ((j < 10) ? RH_l : RL_l) + rg * 1024 + half * 512;
            strd[i] = 1024;
        }
        srcp[i] += l * 8;
    }

    f32x4 hp[5];
#pragma unroll
    for (int f = 0; f < 5; f++) hp[f] = (f32x4){0.f, 0.f, 0.f, 0.f};

#pragma unroll
    for (int i = 0; i < 4; i++) { gload16(srcp[i], dstp[i]); srcp[i] += strd[i]; }
    __syncthreads();
#pragma unroll
    for (int i = 4; i < 9; i++) { gload16(srcp[i], dstp[i]); srcp[i] += strd[i]; }

    for (int tt = 0; tt < 16; tt++) {
        __builtin_amdgcn_s_setprio(1);
#pragma unroll
        for (int tf = 0; tf < 4; tf++) {
            int o0 = tf * 1024 + lg * 128 + lr * 8;
            int o1 = tf * 1024 + (4 + lg) * 128 + lr * 8;
            bf16x8 mh0 = *reinterpret_cast<const bf16x8*>(MH_l + o0);
            bf16x8 mh1 = *reinterpret_cast<const bf16x8*>(MH_l + o1);
            bf16x8 ml0 = *reinterpret_cast<const bf16x8*>(ML_l + o0);
            bf16x8 ml1 = *reinterpret_cast<const bf16x8*>(ML_l + o1);
            f32x4 a = (f32x4){0.f, 0.f, 0.f, 0.f};
            a = MFMA(pah0, mh0, a);
            a = MFMA(pah0, ml0, a);
            a = MFMA(pal0, mh0, a);
            a = MFMA(pah1, mh1, a);
            a = MFMA(pah1, ml1, a);
            a = MFMA(pal1, mh1, a);
#pragma unroll
            for (int r = 0; r < 4; r++)
                Lt[wv * 16 + lg * 4 + r][tf * 16 + lr] = cvt_bf16(fast_tanh(a[r]));
        }
        __builtin_amdgcn_s_setprio(0);
        __syncthreads();                    // drains R(tt); M free
        if (tt < 15) {
#pragma unroll
            for (int i = 0; i < 4; i++) { gload16(srcp[i], dstp[i]); srcp[i] += strd[i]; }
        }
        bf16x8 bt0 = *reinterpret_cast<const bf16x8*>(&Lt[wv * 16 + lr][lg * 8]);
        bf16x8 bt1 = *reinterpret_cast<const bf16x8*>(&Lt[wv * 16 + lr][32 + lg * 8]);
        __builtin_amdgcn_s_setprio(1);
#pragma unroll
        for (int kf = 0; kf < 5; kf++) {
            int o0 = kf * 1024 + lg * 128 + lr * 8;
            int o1 = kf * 1024 + (4 + lg) * 128 + lr * 8;
            bf16x8 rh0 = *reinterpret_cast<const bf16x8*>(RH_l + o0);
            bf16x8 rh1 = *reinterpret_cast<const bf16x8*>(RH_l + o1);
            bf16x8 rl0 = *reinterpret_cast<const bf16x8*>(RL_l + o0);
            bf16x8 rl1 = *reinterpret_cast<const bf16x8*>(RL_l + o1);
            hp[kf] = MFMA(rh0, bt0, hp[kf]);
            hp[kf] = MFMA(rl0, bt0, hp[kf]);
            hp[kf] = MFMA(rh1, bt1, hp[kf]);
            hp[kf] = MFMA(rl1, bt1, hp[kf]);
        }
        __builtin_amdgcn_s_setprio(0);
        __syncthreads();                    // drains M(tt+1); R free
        if (tt < 15) {
#pragma unroll
            for (int i = 4; i < 9; i++) { gload16(srcp[i], dstp[i]); srcp[i] += strd[i]; }
        }
    }

    int n = nc0 + wv * 16 + lr;
    float partial = 0.f;
#pragma unroll
    for (int kf = 0; kf < 5; kf++)
#pragma unroll
        for (int r = 0; r < 4; r++) {
            int k = kf * 16 + lg * 4 + r;
            size_t idx = tix((size_t)b * K + k, n, 64);
            float pp = bf2f(Phi[idx]) + bf2f(Plo[idx]);
            partial += whp[k] * fast_tanh(pp + hp[kf][r]);
        }
    partial += __shfl_xor(partial, 16);
    partial += __shfl_xor(partial, 32);
    if (lg == 0) logits_p[(size_t)b * N + n] = partial;
}

DEV void hr_body(int b, int tc0, unsigned short* smem,
                 const unsigned short* __restrict__ Mhi, const unsigned short* __restrict__ Mlo,
                 const unsigned short* __restrict__ PsH, const unsigned short* __restrict__ PsL,
                 const unsigned short* __restrict__ Phi, const unsigned short* __restrict__ Plo,
                 const unsigned short* __restrict__ Rhi, const unsigned short* __restrict__ Rlo,
                 const float* __restrict__ whr, float* __restrict__ logits_r) {
    unsigned short* PsH_l = smem;
    unsigned short* PsL_l = smem + 4096;
    unsigned short* PpH_l = smem + 8192;
    unsigned short* PpL_l = smem + 13312;
    typedef unsigned short LtRow[72];
    LtRow* Lt = reinterpret_cast<LtRow*>(smem + 18432);
    int tid = threadIdx.x, l = tid & 63, wv = tid >> 6;
    int lr = l & 15, lg = l >> 4;

    size_t mrow = (size_t)b * T + tc0 + wv * 16 + lr;
    size_t m0 = tix(mrow, lg * 8, 8), m1 = tix(mrow, 32 + lg * 8, 8);
    bf16x8 mh0 = *reinterpret_cast<const bf16x8*>(Mhi + m0);
    bf16x8 mh1 = *reinterpret_cast<const bf16x8*>(Mhi + m1);
    bf16x8 ml0 = *reinterpret_cast<const bf16x8*>(Mlo + m0);
    bf16x8 ml1 = *reinterpret_cast<const bf16x8*>(Mlo + m1);

    const unsigned short* srcp[9];
    unsigned short* dstp[9];
    int strd[9];
#pragma unroll
    for (int i = 0; i < 9; i++) {
        int c = wv + i * 4;
        if (c < 8) {
            srcp[i] = PsH + (size_t)b * N * 64 + c * 512;
            dstp[i] = PsH_l + c * 512;
            strd[i] = 4096;
        } else if (c < 16) {
            srcp[i] = PsL + (size_t)b * N * 64 + (c - 8) * 512;
            dstp[i] = PsL_l + (c - 8) * 512;
            strd[i] = 4096;
        } else {
            int j = c - 16, jj = (j < 10) ? j : j - 10;
            int rg = jj >> 1, half = jj & 1;
            srcp[i] = ((j < 10) ? Phi : Plo) + (size_t)(b * 5 + rg) * 8192 + half * 512;
            dstp[i] = ((j < 10) ? PpH_l : PpL_l) + rg * 1024 + half * 512;
            strd[i] = 1024;
        }
        srcp[i] += l * 8;
    }

    f32x4 hr[5];
#pragma unroll
    for (int f = 0; f < 5; f++) hr[f] = (f32x4){0.f, 0.f, 0.f, 0.f};

#pragma unroll
    for (int i = 0; i < 4; i++) { gload16(srcp[i], dstp[i]); srcp[i] += strd[i]; }
    __syncthreads();
#pragma unroll
    for (int i = 4; i < 9; i++) { gload16(srcp[i], dstp[i]); srcp[i] += strd[i]; }

    for (int nt = 0; nt < 8; nt++) {
        __builtin_amdgcn_s_setprio(1);
#pragma unroll
        for (int nf = 0; nf < 4; nf++) {
            int o0 = nf * 1024 + lg * 128 + lr * 8;
            int o1 = nf * 1024 + (4 + lg) * 128 + lr * 8;
            bf16x8 ph0 = *reinterpret_cast<const bf16x8*>(PsH_l + o0);
            bf16x8 ph1 = *reinterpret_cast<const bf16x8*>(PsH_l + o1);
            bf16x8 pl0 = *reinterpret_cast<const bf16x8*>(PsL_l + o0);
            bf16x8 pl1 = *reinterpret_cast<const bf16x8*>(PsL_l + o1);
            f32x4 a = (f32x4){0.f, 0.f, 0.f, 0.f};
            a = MFMA(mh0, ph0, a);
            a = MFMA(mh0, pl0, a);
            a = MFMA(ml0, ph0, a);
            a = MFMA(mh1, ph1, a);
            a = MFMA(mh1, pl1, a);
            a = MFMA(ml1, ph1, a);
#pragma unroll
            for (int r = 0; r < 4; r++)
                Lt[wv * 16 + lg * 4 + r][nf * 16 + lr] = cvt_bf16(fast_tanh(a[r]));
        }
        __builtin_amdgcn_s_setprio(0);
        __syncthreads();
        if (nt < 7) {
#pragma unroll
            for (int i = 0; i < 4; i++) { gload16(srcp[i], dstp[i]); srcp[i] += strd[i]; }
        }
        bf16x8 bt0 = *reinterpret_cast<const bf16x8*>(&Lt[wv * 16 + lr][lg * 8]);
        bf16x8 bt1 = *reinterpret_cast<const bf16x8*>(&Lt[wv * 16 + lr][32 + lg * 8]);
        __builtin_amdgcn_s_setprio(1);
#pragma unroll
        for (int kf = 0; kf < 5; kf++) {
            int o0 = kf * 1024 + lg * 128 + lr * 8;
            int o1 = kf * 1024 + (4 + lg) * 128 + lr * 8;
            bf16x8 qh0 = *reinterpret_cast<const bf16x8*>(PpH_l + o0);
            bf16x8 qh1 = *reinterpret_cast<const bf16x8*>(PpH_l + o1);
            bf16x8 ql0 = *reinterpret_cast<const bf16x8*>(PpL_l + o0);
            bf16x8 ql1 = *reinterpret_cast<const bf16x8*>(PpL_l + o1);
            hr[kf] = MFMA(qh0, bt0, hr[kf]);
            hr[kf] = MFMA(ql0, bt0, hr[kf]);
            hr[kf] = MFMA(qh1, bt1, hr[kf]);
            hr[kf] = MFMA(ql1, bt1, hr[kf]);
        }
        __builtin_amdgcn_s_setprio(0);
        __syncthreads();
        if (nt < 7) {
#pragma unroll
            for (int i = 4; i < 9; i++) { gload16(srcp[i], dstp[i]); srcp[i] += strd[i]; }
        }
    }

    int t = tc0 + wv * 16 + lr;
    float partial = 0.f;
#pragma unroll
    for (int kf = 0; kf < 5; kf++)
#pragma unroll
        for (int r = 0; r < 4; r++) {
            int k = kf * 16 + lg * 4 + r;
            size_t idx = tix((size_t)b * K + k, t, 128);
            float rr = bf2f(Rhi[idx]) + bf2f(Rlo[idx]);
            partial += whr[k] * fast_tanh(rr + hr[kf][r]);
        }
    partial += __shfl_xor(partial, 16);
    partial += __shfl_xor(partial, 32);
    if (lg == 0) logits_r[(size_t)b * T + t] = partial;
}

// ---------------------------------------------------------------------------
// Merged fused kernel (v13 grid): per b, 24 roles (8 hp + 16 hr).
// lin = (b%8) + 8*((b/8)*24 + role): all of a b's blocks on one XCD.
__global__ __launch_bounds__(256) void k_fused(
    const unsigned short* __restrict__ Mhi, const unsigned short* __restrict__ Mlo,
    const unsigned short* __restrict__ PsH, const unsigned short* __restrict__ PsL,
    const unsigned short* __restrict__ Rhi, const unsigned short* __restrict__ Rlo,
    const unsigned short* __restrict__ Phi, const unsigned short* __restrict__ Plo,
    const float* __restrict__ whp, const float* __restrict__ whr,
    float* __restrict__ logits_p, float* __restrict__ logits_r) {
    __shared__ __align__(16) unsigned short smem[23040];   // 46,080 B
    int lin = blockIdx.x;
    int x = lin & 7, j = lin >> 3;
    int bg = j / 24, role = j - bg * 24;
    int b = bg * 8 + x;
    if (role < 8) {
        hp_body(b, role * 64, smem, Mhi, Mlo, PsH, PsL, Rhi, Rlo, Phi, Plo, whp, logits_p);
    } else {
        hr_body(b, (role - 8) * 64, smem, Mhi, Mlo, PsH, PsL, Phi, Plo, Rhi, Rlo, whr, logits_r);
    }
}

// ===========================================================================
// Merged softpool
// ===========================================================================
DEV void softpool_body(const float* __restrict__ logits, const float* __restrict__ X,
                       float* __restrict__ out, int S, int off, int cy,
                       float* sm, float* red) {
    int b = blockIdx.x, tid = threadIdx.x;
    int c0 = cy * 128;
    for (int i = tid; i < S; i += 256) sm[i] = logits[(size_t)b * S + i];
    __syncthreads();
    float m = -1e30f;
    for (int i = tid; i < S; i += 256) m = fmaxf(m, sm[i]);
    red[tid] = m;
    __syncthreads();
    for (int s = 128; s > 0; s >>= 1) {
        if (tid < s) red[tid] = fmaxf(red[tid], red[tid + s]);
        __syncthreads();
    }
    float mx = red[0];
    __syncthreads();
    float psum = 0.f;
    for (int i = tid; i < S; i += 256) {
        float e = __expf(sm[i] - mx);
        sm[i] = e;
        psum += e;
    }
    red[tid] = psum;
    __syncthreads();
    for (int s = 128; s > 0; s >>= 1) {
        if (tid < s) red[tid] += red[tid + s];
        __syncthreads();
    }
    float inv = 1.f / red[0];
    __syncthreads();
    int d = tid & 63, g = tid >> 6;
    float acc = 0.f;
    for (int n = c0 + g; n < c0 + 128; n += 4) acc += sm[n] * X[((size_t)b * S + n) * 64 + d];
    red[tid] = acc * inv;
    __syncthreads();
    if (g == 0)
        atomicAdd(&out[(size_t)b * 128 + off + d],
                  red[d] + red[64 + d] + red[128 + d] + red[192 + d]);
}

__global__ __launch_bounds__(256) void k_softpool2(
    const float* __restrict__ logits_p, const float* __restrict__ logits_r,
    const float* __restrict__ post, const float* __restrict__ review,
    float* __restrict__ out) {
    __shared__ float sm[1024];
    __shared__ float red[256];
    int y = blockIdx.y;
    if (y < N / 128) softpool_body(logits_p, post, out, N, 0, y, sm, red);
    else             softpool_body(logits_r, review, out, T, 64, y - N / 128, sm, red);
}

// ---------------------------------------------------------------------------
extern "C" void kernel_launch(void* const* d_in, const int* in_sizes, int n_in,
                              void* d_out, int out_size, void* d_ws, size_t ws_size,
                              hipStream_t stream) {
    const float* review = (const float*)d_in[0];
    const float* post   = (const float*)d_in[1];
    const float* Wl     = (const float*)d_in[2];
    const float* Wr     = (const float*)d_in[3];
    const float* Wp     = (const float*)d_in[4];
    const float* whr    = (const float*)d_in[5];
    const float* whp    = (const float*)d_in[6];
    float* out = (float*)d_out;

    char* p = (char*)d_ws;
    unsigned short* Mhi = (unsigned short*)p;  p += (size_t)B * T * D * 2;
    unsigned short* Mlo = (unsigned short*)p;  p += (size_t)B * T * D * 2;
    unsigned short* PsH = (unsigned short*)p;  p += (size_t)B * N * D * 2;
    unsigned short* PsL = (unsigned short*)p;  p += (size_t)B * N * D * 2;
    unsigned short* Rhi = (unsigned short*)p;  p += (size_t)B * K * T * 2;
    unsigned short* Rlo = (unsigned short*)p;  p += (size_t)B * K * T * 2;
    unsigned short* Phi = (unsigned short*)p;  p += (size_t)B * K * N * 2;
    unsigned short* Plo = (unsigned short*)p;  p += (size_t)B * K * N * 2;
    float* logits_p = (float*)p;        p += (size_t)B * N * 4;
    float* logits_r = (float*)p;        p += (size_t)B * T * 4;

    k_prelude<<<dim3(4640), dim3(256), 0, stream>>>(review, post, Wl, Wr, Wp,
                                                    Mhi, Mlo, PsH, PsL, Rhi, Rlo,
                                                    Phi, Plo, out);
    k_fused<<<dim3(1536), dim3(256), 0, stream>>>(Mhi, Mlo, PsH, PsL, Rhi, Rlo,
                                                  Phi, Plo, whp, whr, logits_p, logits_r);
    k_softpool2<<<dim3(B, 12), dim3(256), 0, stream>>>(logits_p, logits_r, post, review, out);
}